// Round 1
// baseline (605.596 us; speedup 1.0000x reference)
//
#include <hip/hip_runtime.h>
#include <hip/hip_bf16.h>

#define BB 128
#define TT 20
#define CCH 4
#define HWE 4096
#define DD 128
#define MM (BB*TT*CCH)   // 10240

typedef float f32x4 __attribute__((ext_vector_type(4)));
typedef __bf16 bf16x8 __attribute__((ext_vector_type(8)));

// exact RNE float->bf16 (matches v_cvt semantics for finite values)
static __device__ __forceinline__ unsigned short f2bf(float f) {
    unsigned int u = __builtin_bit_cast(unsigned int, f);
    unsigned int r = u + 0x7FFFu + ((u >> 16) & 1u);
    return (unsigned short)(r >> 16);
}
static __device__ __forceinline__ unsigned int pk2(float a, float b) {
    return (unsigned int)f2bf(a) | ((unsigned int)f2bf(b) << 16);
}

// ---------------- prep: W_emb -> MFMA B-fragment-linear bf16 ----------------
// layout: [ks(128)][n0(8)][lane(64)][j(8)], value = W_emb[k= ks*32+(lane>>4)*8+j][n= n0*16+(lane&15)]
__global__ __launch_bounds__(256) void prep_emb_w(const float* __restrict__ Wemb,
                                                  unsigned short* __restrict__ bfrag) {
    int tid = blockIdx.x * 256 + threadIdx.x;  // 0..524287
    int j = tid & 7, lane = (tid >> 3) & 63, n0 = (tid >> 9) & 7, ks = tid >> 12;
    int k = ks * 32 + (lane >> 4) * 8 + j;
    int n = n0 * 16 + (lane & 15);
    bfrag[tid] = f2bf(Wemb[k * DD + n]);
}

// ---------------- prep: [Wq0|Wkv0|Wq1|Wkv1] (K=128,N=192) -> frag layout per block i ----
__global__ __launch_bounds__(256) void prep_qkv_w(const float* __restrict__ Wq,
                                                  const float* __restrict__ Wkv,
                                                  unsigned short* __restrict__ wfrag) {
    int tid = blockIdx.x * 256 + threadIdx.x;  // 0..49151
    int j = tid & 7; int idx = tid >> 3;
    int lane = idx & 63; idx >>= 6;
    int n0 = idx % 12; idx /= 12;
    int ks = idx & 3; int i = idx >> 2;
    int k = ks * 32 + (lane >> 4) * 8 + j;
    int n = n0 * 16 + (lane & 15);
    float v;
    if (n < 32)       v = Wq [((i*2+0)*DD + k)*32 + n];
    else if (n < 96)  v = Wkv[((i*2+0)*DD + k)*64 + (n-32)];
    else if (n < 128) v = Wq [((i*2+1)*DD + k)*32 + (n-96)];
    else              v = Wkv[((i*2+1)*DD + k)*64 + (n-128)];
    wfrag[tid] = f2bf(v);
}

// ---------------- fused noise + embed GEMM + bias + leaky -------------------
// grid 640 (16 rows each), 256 thr = 4 waves, split-K: wave w covers K [w*1024,(w+1)*1024)
__global__ __launch_bounds__(256) void emb_kernel(
    const float* __restrict__ x, const float* __restrict__ n1, const float* __restrict__ n2,
    const unsigned short* __restrict__ bfrag, const float* __restrict__ bemb,
    float* __restrict__ h)
{
    __shared__ unsigned short ast[4][16*72];   // per-wave staging, stride 72 (pad 8)
    __shared__ float red[3][16*132];           // cross-wave reduction, stride 132
    const int wave = threadIdx.x >> 6, lane = threadIdx.x & 63;
    const int quad = lane >> 4, l15 = lane & 15;
    const int row0 = blockIdx.x * 16;

    f32x4 acc[8];
#pragma unroll
    for (int n = 0; n < 8; ++n) acc[n] = (f32x4){0.f,0.f,0.f,0.f};

    const int kw = wave * 1024;
    for (int kc = 0; kc < 16; ++kc) {
        const int kbase = kw + kc * 64;
#pragma unroll
        for (int i = 0; i < 4; ++i) {
            int f = i * 64 + lane;            // 0..255 -> (row, float4-col)
            int r = f >> 4, k4 = f & 15;
            int off = (row0 + r) * HWE + kbase + k4 * 4;
            const float4 a = *reinterpret_cast<const float4*>(x  + off);
            const float4 b = *reinterpret_cast<const float4*>(n1 + off);
            const float4 c = *reinterpret_cast<const float4*>(n2 + off);
            float sx = a.x + 1e-3f*b.x + 1e-4f*c.x;
            float sy = a.y + 1e-3f*b.y + 1e-4f*c.y;
            float sz = a.z + 1e-3f*b.z + 1e-4f*c.z;
            float sw = a.w + 1e-3f*b.w + 1e-4f*c.w;
            uint2 p; p.x = pk2(sx, sy); p.y = pk2(sz, sw);
            *reinterpret_cast<uint2*>(&ast[wave][r*72 + k4*4]) = p;
        }
        // same-wave LDS RAW: compiler inserts waitcnt, no barrier needed
#pragma unroll
        for (int s = 0; s < 2; ++s) {
            bf16x8 af = *reinterpret_cast<const bf16x8*>(&ast[wave][l15*72 + s*32 + quad*8]);
            const int ks = (kbase >> 5) + s;
#pragma unroll
            for (int n = 0; n < 8; ++n) {
                const bf16x8 bf = *reinterpret_cast<const bf16x8*>(bfrag + (((ks*8 + n)*64 + lane) << 3));
                acc[n] = __builtin_amdgcn_mfma_f32_16x16x32_bf16(af, bf, acc[n], 0, 0, 0);
            }
        }
    }

    if (wave != 0) {
#pragma unroll
        for (int n = 0; n < 8; ++n)
#pragma unroll
            for (int rg = 0; rg < 4; ++rg)
                red[wave-1][(quad*4+rg)*132 + n*16 + l15] = acc[n][rg];
    }
    __syncthreads();
    if (wave == 0) {
#pragma unroll
        for (int n = 0; n < 8; ++n) {
            const int col = n*16 + l15;
            const float bias = bemb[col];
#pragma unroll
            for (int rg = 0; rg < 4; ++rg) {
                const int idx = (quad*4+rg)*132 + n*16 + l15;
                float v = acc[n][rg] + red[0][idx] + red[1][idx] + red[2][idx] + bias;
                v = v > 0.f ? v : 0.2f * v;
                h[(row0 + quad*4 + rg)*DD + col] = v;
            }
        }
    }
}

// ---------------- qkv GEMM: h[10240,128] @ Wcat[128,192] (bf16 MFMA) --------
// grid 640 x 64 thr (1 wave, 16 rows, full K=128)
__global__ __launch_bounds__(64) void qkv_kernel(
    const float* __restrict__ h, const unsigned short* __restrict__ wfrag,
    float* __restrict__ qkv)
{
    __shared__ unsigned short ast[16*136];
    const int lane = threadIdx.x & 63;
    const int quad = lane >> 4, l15 = lane & 15;
    const int row0 = blockIdx.x * 16;
#pragma unroll
    for (int i = 0; i < 8; ++i) {
        int f = i * 64 + lane;                 // 0..511
        int r = f >> 5, c4 = f & 31;
        const float4 a = *reinterpret_cast<const float4*>(h + (row0 + r) * DD + c4 * 4);
        uint2 p; p.x = pk2(a.x, a.y); p.y = pk2(a.z, a.w);
        *reinterpret_cast<uint2*>(&ast[r*136 + c4*4]) = p;
    }
    f32x4 acc[12];
#pragma unroll
    for (int n = 0; n < 12; ++n) acc[n] = (f32x4){0.f,0.f,0.f,0.f};
#pragma unroll
    for (int ks = 0; ks < 4; ++ks) {
        bf16x8 af = *reinterpret_cast<const bf16x8*>(&ast[l15*136 + ks*32 + quad*8]);
#pragma unroll
        for (int n = 0; n < 12; ++n) {
            const bf16x8 bf = *reinterpret_cast<const bf16x8*>(wfrag + (((ks*12 + n)*64 + lane) << 3));
            acc[n] = __builtin_amdgcn_mfma_f32_16x16x32_bf16(af, bf, acc[n], 0, 0, 0);
        }
    }
#pragma unroll
    for (int n = 0; n < 12; ++n)
#pragma unroll
        for (int rg = 0; rg < 4; ++rg)
            qkv[(row0 + quad*4 + rg)*192 + n*16 + l15] = acc[n][rg];
}

// ---------------- attention core, T axis (seq len 20) -----------------------
// grid 512 = (b,c); 192 thr; thread = (tq, head)
__global__ __launch_bounds__(192) void attn_t(const float* __restrict__ qkv,
                                              float* __restrict__ ocat)
{
    __shared__ float sq[20*96];
    const int b = blockIdx.x >> 2, c = blockIdx.x & 3;
    for (int idx = threadIdx.x; idx < 20*96; idx += 192) {
        int r = idx / 96, cc = idx - r*96;
        sq[idx] = qkv[(b*80 + r*4 + c)*192 + cc];
    }
    __syncthreads();
    if (threadIdx.x < 160) {
        const int tq = threadIdx.x >> 3, hd = threadIdx.x & 7;
        float qv[4];
#pragma unroll
        for (int d = 0; d < 4; ++d) qv[d] = sq[tq*96 + hd*4 + d];
        float dots[20]; float mx = -1e30f;
#pragma unroll
        for (int tk = 0; tk < 20; ++tk) {
            const float* kk = &sq[tk*96 + 32 + hd*4];
            float dt = (qv[0]*kk[0] + qv[1]*kk[1] + qv[2]*kk[2] + qv[3]*kk[3]) * 0.5f;
            dots[tk] = dt; mx = fmaxf(mx, dt);
        }
        float sum = 0.f;
#pragma unroll
        for (int tk = 0; tk < 20; ++tk) { float e = __expf(dots[tk]-mx); dots[tk] = e; sum += e; }
        const float inv = 1.f / sum;
        float o0=0.f,o1=0.f,o2=0.f,o3=0.f;
#pragma unroll
        for (int tk = 0; tk < 20; ++tk) {
            const float* vv = &sq[tk*96 + 64 + hd*4];
            float w = dots[tk];
            o0 += w*vv[0]; o1 += w*vv[1]; o2 += w*vv[2]; o3 += w*vv[3];
        }
        float* op = &ocat[(b*80 + tq*4 + c)*64 + hd*4];
        op[0]=o0*inv; op[1]=o1*inv; op[2]=o2*inv; op[3]=o3*inv;
    }
}

// ---------------- attention core, C axis (seq len 4) ------------------------
// grid 128 = b; 640 thr = (t, cq, head)
__global__ __launch_bounds__(640) void attn_c(const float* __restrict__ qkv,
                                              float* __restrict__ ocat)
{
    __shared__ float sc[80*96];
    const int b = blockIdx.x;
    for (int idx = threadIdx.x; idx < 80*96; idx += 640) {
        int r = idx / 96, cc = idx - r*96;
        sc[idx] = qkv[(b*80 + r)*192 + 96 + cc];
    }
    __syncthreads();
    const int t = threadIdx.x >> 5, rem = threadIdx.x & 31;
    const int cq = rem >> 3, hd = rem & 7;
    float qv[4];
#pragma unroll
    for (int d = 0; d < 4; ++d) qv[d] = sc[(t*4+cq)*96 + hd*4 + d];
    float dots[4]; float mx = -1e30f;
#pragma unroll
    for (int ck = 0; ck < 4; ++ck) {
        const float* kk = &sc[(t*4+ck)*96 + 32 + hd*4];
        float dt = (qv[0]*kk[0] + qv[1]*kk[1] + qv[2]*kk[2] + qv[3]*kk[3]) * 0.5f;
        dots[ck] = dt; mx = fmaxf(mx, dt);
    }
    float sum = 0.f;
#pragma unroll
    for (int ck = 0; ck < 4; ++ck) { float e = __expf(dots[ck]-mx); dots[ck] = e; sum += e; }
    const float inv = 1.f / sum;
    float o0=0.f,o1=0.f,o2=0.f,o3=0.f;
#pragma unroll
    for (int ck = 0; ck < 4; ++ck) {
        const float* vv = &sc[(t*4+ck)*96 + 64 + hd*4];
        float w = dots[ck];
        o0 += w*vv[0]; o1 += w*vv[1]; o2 += w*vv[2]; o3 += w*vv[3];
    }
    float* op = &ocat[(b*80 + t*4 + cq)*64 + 32 + hd*4];
    op[0]=o0*inv; op[1]=o1*inv; op[2]=o2*inv; op[3]=o3*inv;
}

// ---------------- out-proj both axes + bias + leaky -> h --------------------
// grid 1280 x 256; thread = (row, col/4)
__global__ __launch_bounds__(256) void outproj(
    const float* __restrict__ ocat, const float* __restrict__ Wout,
    const float* __restrict__ bout, const int i, float* __restrict__ h)
{
    const int g = blockIdx.x * 256 + threadIdx.x;   // 0..327679
    const int r = g >> 5, c4 = g & 31;
    const float* w0 = Wout + (i*2+0)*32*DD;
    const float* w1 = Wout + (i*2+1)*32*DD;
    f32x4 acc = (f32x4){0.f,0.f,0.f,0.f};
#pragma unroll 8
    for (int k = 0; k < 32; ++k) {
        const float a = ocat[r*64 + k];
        const float4 w = *reinterpret_cast<const float4*>(w0 + k*DD + c4*4);
        acc.x += a*w.x; acc.y += a*w.y; acc.z += a*w.z; acc.w += a*w.w;
    }
#pragma unroll 8
    for (int k = 0; k < 32; ++k) {
        const float a = ocat[r*64 + 32 + k];
        const float4 w = *reinterpret_cast<const float4*>(w1 + k*DD + c4*4);
        acc.x += a*w.x; acc.y += a*w.y; acc.z += a*w.z; acc.w += a*w.w;
    }
    const float4 b0 = *reinterpret_cast<const float4*>(bout + (i*2+0)*DD + c4*4);
    const float4 b1 = *reinterpret_cast<const float4*>(bout + (i*2+1)*DD + c4*4);
    float v0 = acc.x + b0.x + b1.x;
    float v1 = acc.y + b0.y + b1.y;
    float v2 = acc.z + b0.z + b1.z;
    float v3 = acc.w + b0.w + b1.w;
    v0 = v0 > 0.f ? v0 : 0.2f*v0;
    v1 = v1 > 0.f ? v1 : 0.2f*v1;
    v2 = v2 > 0.f ? v2 : 0.2f*v2;
    v3 = v3 > 0.f ? v3 : 0.2f*v3;
    float4 out; out.x=v0; out.y=v1; out.z=v2; out.w=v3;
    *reinterpret_cast<float4*>(h + r*DD + c4*4) = out;
}

// ---------------- decoder: per-batch dot + sigmoid --------------------------
__global__ __launch_bounds__(256) void decoder(const float* __restrict__ h,
                                               const float* __restrict__ Wd,
                                               const float* __restrict__ bd,
                                               float* __restrict__ out)
{
    __shared__ float partials[4];
    const int b = blockIdx.x;
    float p = 0.f;
    for (int idx = threadIdx.x; idx < 10240; idx += 256)
        p += h[b*10240 + idx] * Wd[idx];
#pragma unroll
    for (int off = 32; off > 0; off >>= 1) p += __shfl_down(p, off);
    if ((threadIdx.x & 63) == 0) partials[threadIdx.x >> 6] = p;
    __syncthreads();
    if (threadIdx.x == 0) {
        float s = partials[0] + partials[1] + partials[2] + partials[3] + bd[0];
        out[b] = 1.f / (1.f + __expf(-s));
    }
}

extern "C" void kernel_launch(void* const* d_in, const int* in_sizes, int n_in,
                              void* d_out, int out_size, void* d_ws, size_t ws_size,
                              hipStream_t stream)
{
    (void)in_sizes; (void)n_in; (void)out_size; (void)ws_size;
    const float* x    = (const float*)d_in[0];
    const float* n1   = (const float*)d_in[1];
    const float* n2   = (const float*)d_in[2];
    const float* Wemb = (const float*)d_in[3];
    const float* bemb = (const float*)d_in[4];
    const float* Wq   = (const float*)d_in[5];
    const float* Wkv  = (const float*)d_in[6];
    const float* Wout = (const float*)d_in[7];
    const float* bout = (const float*)d_in[8];
    const float* Wd   = (const float*)d_in[9];
    const float* bd   = (const float*)d_in[10];
    float* out = (float*)d_out;

    char* ws = (char*)d_ws;
    unsigned short* bfrag = (unsigned short*)(ws);                 // 1,048,576 B
    unsigned short* wfrag = (unsigned short*)(ws + 1048576);       //    98,304 B
    float* h    = (float*)(ws + 1146880);                          // 5,242,880 B
    float* qkv  = (float*)(ws + 6389760);                          // 7,864,320 B
    float* ocat = (float*)(ws + 14254080);                         // 2,621,440 B (end ~16.1 MB)

    prep_emb_w<<<2048, 256, 0, stream>>>(Wemb, bfrag);
    prep_qkv_w<<<192, 256, 0, stream>>>(Wq, Wkv, wfrag);
    emb_kernel<<<640, 256, 0, stream>>>(x, n1, n2, bfrag, bemb, h);
    for (int i = 0; i < 2; ++i) {
        qkv_kernel<<<640, 64, 0, stream>>>(h, wfrag + i*24576, qkv);
        attn_t<<<512, 192, 0, stream>>>(qkv, ocat);
        attn_c<<<128, 640, 0, stream>>>(qkv, ocat);
        outproj<<<1280, 256, 0, stream>>>(ocat, Wout, bout, i, h);
    }
    decoder<<<128, 256, 0, stream>>>(h, Wd, bd, out);
}

// Round 2
// 484.938 us; speedup vs baseline: 1.2488x; 1.2488x over previous
//
#include <hip/hip_runtime.h>
#include <hip/hip_bf16.h>

typedef float f32x4 __attribute__((ext_vector_type(4)));
typedef __bf16 bf16x8 __attribute__((ext_vector_type(8)));

// exact RNE float->bf16
static __device__ __forceinline__ unsigned short f2bf(float f) {
    unsigned int u = __builtin_bit_cast(unsigned int, f);
    unsigned int r = u + 0x7FFFu + ((u >> 16) & 1u);
    return (unsigned short)(r >> 16);
}
static __device__ __forceinline__ unsigned int pk2(float a, float b) {
    return (unsigned int)f2bf(a) | ((unsigned int)f2bf(b) << 16);
}
static __device__ __forceinline__ bf16x8 pack8(float s0,float s1,float s2,float s3,
                                               float s4,float s5,float s6,float s7) {
    union { unsigned int u[4]; bf16x8 v; } z;
    z.u[0] = pk2(s0,s1); z.u[1] = pk2(s2,s3); z.u[2] = pk2(s4,s5); z.u[3] = pk2(s6,s7);
    return z.v;
}

// frag workspace layout (shorts):
//   [0, 524288)            : W_emb B-frags   (ks 128)(n0 8)(lane 64)(j 8)
//   [524288, +49152)       : qkv W B-frags   (i 2)(ks 4)(n0 12)(lane)(j)
//   [573440, +16384)       : Wout B-frags    (i 2)(ks 2)(n0 8)(lane)(j)
#define QKVF 524288
#define WOF  573440

// ---------------- one prep dispatch for all weight fragments ----------------
__global__ __launch_bounds__(256) void prep_all(
    const float* __restrict__ Wemb, const float* __restrict__ Wq,
    const float* __restrict__ Wkv,  const float* __restrict__ Wout,
    unsigned short* __restrict__ frag)
{
    const int b = blockIdx.x, t = threadIdx.x;
    if (b < 2048) {
        int tid = b*256 + t;               // = k*128 + n  (coalesced read)
        int k = tid >> 7, n = tid & 127;
        int ks = k >> 5, quad = (k >> 3) & 3, j = k & 7;
        int n0 = n >> 4, l15 = n & 15;
        int o = (((ks*8 + n0)*64) + quad*16 + l15)*8 + j;
        frag[o] = f2bf(Wemb[tid]);
    } else if (b < 2240) {
        int tid = (b-2048)*256 + t;        // 0..49151
        int j = tid & 7; int idx = tid >> 3;
        int lane = idx & 63; idx >>= 6;
        int n0 = idx % 12; idx /= 12;
        int ks = idx & 3; int i = idx >> 2;
        int k = ks*32 + (lane>>4)*8 + j;
        int n = n0*16 + (lane & 15);
        float v;
        if (n < 32)       v = Wq [((i*2+0)*128 + k)*32 + n];
        else if (n < 96)  v = Wkv[((i*2+0)*128 + k)*64 + (n-32)];
        else if (n < 128) v = Wq [((i*2+1)*128 + k)*32 + (n-96)];
        else              v = Wkv[((i*2+1)*128 + k)*64 + (n-128)];
        frag[QKVF + tid] = f2bf(v);
    } else {
        int tid = (b-2240)*256 + t;        // 0..16383
        int j = tid & 7; int idx = tid >> 3;
        int lane = idx & 63; idx >>= 6;
        int n0 = idx & 7; idx >>= 3;
        int ks = idx & 1; int i = idx >> 1;
        int k = ks*32 + (lane>>4)*8 + j;   // 0..63
        int n = n0*16 + (lane & 15);
        float v = (k < 32) ? Wout[((i*2+0)*32 + k)*128 + n]
                           : Wout[((i*2+1)*32 + (k-32))*128 + n];
        frag[WOF + i*8192 + ((ks*8+n0)*64 + lane)*8 + j] = f2bf(v);
    }
}

// ---------------- fused noise + embed GEMM, split-K(2) to partials ----------
// grid 1280: (r16 = b>>1, kq = b&1); 256 thr = 4 waves; wave covers 512 K
__global__ __launch_bounds__(256) void emb_kernel(
    const float* __restrict__ x, const float* __restrict__ n1, const float* __restrict__ n2,
    const unsigned short* __restrict__ bfrag, float* __restrict__ part)
{
    __shared__ float red[3][16*132];
    const int wave = threadIdx.x >> 6, lane = threadIdx.x & 63;
    const int quad = lane >> 4, l15 = lane & 15;
    const int r16 = blockIdx.x >> 1, kq = blockIdx.x & 1;
    const int row = r16*16 + l15;
    const int off0 = row*4096 + kq*2048 + wave*512 + quad*8;
    const float* px = x  + off0;
    const float* pn = n1 + off0;
    const float* pc = n2 + off0;
    const unsigned short* bp = bfrag + (kq*64 + wave*16)*4096 + lane*8;

    f32x4 acc[8];
#pragma unroll
    for (int n = 0; n < 8; ++n) acc[n] = (f32x4){0.f,0.f,0.f,0.f};

    float4 a0 = *(const float4*)(px);   float4 a1 = *(const float4*)(px+4);
    float4 b0 = *(const float4*)(pn);   float4 b1 = *(const float4*)(pn+4);
    float4 c0 = *(const float4*)(pc);   float4 c1 = *(const float4*)(pc+4);

    for (int kc = 0; kc < 16; ++kc) {
        // B-frags issued first (L2-hot) so MFMA waits only on them
        bf16x8 bf[8];
#pragma unroll
        for (int n = 0; n < 8; ++n)
            bf[n] = *(const bf16x8*)(bp + kc*4096 + n*512);
        // prefetch next K-chunk (HBM); last iter re-reads current (L1 hit, dead)
        const int ko = (kc < 15 ? kc+1 : kc) * 32;
        float4 na0 = *(const float4*)(px + ko);  float4 na1 = *(const float4*)(px + ko + 4);
        float4 nb0 = *(const float4*)(pn + ko);  float4 nb1 = *(const float4*)(pn + ko + 4);
        float4 nc0 = *(const float4*)(pc + ko);  float4 nc1 = *(const float4*)(pc + ko + 4);

        float s0 = a0.x + 1e-3f*b0.x + 1e-4f*c0.x;
        float s1 = a0.y + 1e-3f*b0.y + 1e-4f*c0.y;
        float s2 = a0.z + 1e-3f*b0.z + 1e-4f*c0.z;
        float s3 = a0.w + 1e-3f*b0.w + 1e-4f*c0.w;
        float s4 = a1.x + 1e-3f*b1.x + 1e-4f*c1.x;
        float s5 = a1.y + 1e-3f*b1.y + 1e-4f*c1.y;
        float s6 = a1.z + 1e-3f*b1.z + 1e-4f*c1.z;
        float s7 = a1.w + 1e-3f*b1.w + 1e-4f*c1.w;
        bf16x8 af = pack8(s0,s1,s2,s3,s4,s5,s6,s7);
#pragma unroll
        for (int n = 0; n < 8; ++n)
            acc[n] = __builtin_amdgcn_mfma_f32_16x16x32_bf16(af, bf[n], acc[n], 0, 0, 0);
        a0 = na0; a1 = na1; b0 = nb0; b1 = nb1; c0 = nc0; c1 = nc1;
    }

    if (wave != 0) {
#pragma unroll
        for (int n = 0; n < 8; ++n)
#pragma unroll
            for (int rg = 0; rg < 4; ++rg)
                red[wave-1][(quad*4+rg)*132 + n*16 + l15] = acc[n][rg];
    }
    __syncthreads();
    if (wave == 0) {
#pragma unroll
        for (int n = 0; n < 8; ++n)
#pragma unroll
            for (int rg = 0; rg < 4; ++rg) {
                const int idx = (quad*4+rg)*132 + n*16 + l15;
                float v = acc[n][rg] + red[0][idx] + red[1][idx] + red[2][idx];
                part[(kq*10240 + r16*16 + quad*4 + rg)*128 + n*16 + l15] = v;
            }
    }
}

// ---------------- mega: reduce+bias+leaky, 2x(qkv+attn+outproj), decoder ----
// grid 128 (one per batch b), 512 thr = 8 waves
#define LDH 132
#define LDQ 200
#define LDO 68
__global__ __launch_bounds__(512) void mega_kernel(
    const float* __restrict__ part, const float* __restrict__ bemb,
    const unsigned short* __restrict__ frag, const float* __restrict__ bout,
    const float* __restrict__ Wd, const float* __restrict__ bd,
    float* __restrict__ out)
{
    __shared__ float hs[80*LDH];
    __shared__ float qs[80*LDQ];
    __shared__ float os[80*LDO];
    __shared__ float red[8];
    const int b = blockIdx.x, tid = threadIdx.x;
    const int wave = tid >> 6, lane = tid & 63;
    const int quad = lane >> 4, l15 = lane & 15;

    // ---- h = leaky(sum of 2 K-partials + bias) ----
#pragma unroll
    for (int e = 0; e < 5; ++e) {
        int idx4 = tid + e*512;          // 0..2559
        int r = idx4 >> 5, c4 = idx4 & 31;
        const float* p = part + (b*80 + r)*128 + c4*4;
        float4 s0 = *(const float4*)(p);
        float4 s1 = *(const float4*)(p + 1310720);
        float4 bb = *(const float4*)(bemb + c4*4);
        float v0 = s0.x + s1.x + bb.x; v0 = v0 > 0.f ? v0 : 0.2f*v0;
        float v1 = s0.y + s1.y + bb.y; v1 = v1 > 0.f ? v1 : 0.2f*v1;
        float v2 = s0.z + s1.z + bb.z; v2 = v2 > 0.f ? v2 : 0.2f*v2;
        float v3 = s0.w + s1.w + bb.w; v3 = v3 > 0.f ? v3 : 0.2f*v3;
        float4 o4; o4.x=v0; o4.y=v1; o4.z=v2; o4.w=v3;
        *(float4*)(&hs[r*LDH + c4*4]) = o4;
    }
    __syncthreads();

    for (int i = 0; i < 2; ++i) {
        const unsigned short* wq = frag + QKVF + i*24576;
        const unsigned short* wo = frag + WOF  + i*8192;
        // ---- qkv = h @ Wcat  (5m x 12n tiles, K=128) ----
        for (int tile = wave; tile < 60; tile += 8) {
            int m = tile / 12, n = tile - m*12;
            f32x4 acc = (f32x4){0.f,0.f,0.f,0.f};
#pragma unroll
            for (int ks = 0; ks < 4; ++ks) {
                const float* ap = &hs[(m*16 + l15)*LDH + ks*32 + quad*8];
                float4 x0 = *(const float4*)ap; float4 x1 = *(const float4*)(ap+4);
                bf16x8 af = pack8(x0.x,x0.y,x0.z,x0.w,x1.x,x1.y,x1.z,x1.w);
                bf16x8 bf = *(const bf16x8*)(wq + ((ks*12 + n)*64 + lane)*8);
                acc = __builtin_amdgcn_mfma_f32_16x16x32_bf16(af, bf, acc, 0, 0, 0);
            }
#pragma unroll
            for (int rg = 0; rg < 4; ++rg)
                qs[(m*16 + quad*4 + rg)*LDQ + n*16 + l15] = acc[rg];
        }
        __syncthreads();
        // ---- attention, both axes (t: len 20; c: len 4) ----
        for (int task = tid; task < 1280; task += 512) {
            if (task < 640) {
                int c = task & 3, rem = task >> 2;
                int tq = rem >> 3, hd = rem & 7;
                const int qrow = tq*4 + c;
                const float* qp = &qs[qrow*LDQ + hd*4];
                float q0 = qp[0], q1 = qp[1], q2 = qp[2], q3 = qp[3];
                float dots[20]; float mx = -1e30f;
#pragma unroll
                for (int tk = 0; tk < 20; ++tk) {
                    const float* kk = &qs[(tk*4+c)*LDQ + 32 + hd*4];
                    float dt = (q0*kk[0] + q1*kk[1] + q2*kk[2] + q3*kk[3]) * 0.5f;
                    dots[tk] = dt; mx = fmaxf(mx, dt);
                }
                float sum = 0.f;
#pragma unroll
                for (int tk = 0; tk < 20; ++tk) { float e = __expf(dots[tk]-mx); dots[tk] = e; sum += e; }
                const float inv = 1.f / sum;
                float o0=0.f,o1=0.f,o2=0.f,o3=0.f;
#pragma unroll
                for (int tk = 0; tk < 20; ++tk) {
                    const float* vv = &qs[(tk*4+c)*LDQ + 64 + hd*4];
                    float w = dots[tk];
                    o0 += w*vv[0]; o1 += w*vv[1]; o2 += w*vv[2]; o3 += w*vv[3];
                }
                float* op = &os[qrow*LDO + hd*4];
                op[0]=o0*inv; op[1]=o1*inv; op[2]=o2*inv; op[3]=o3*inv;
            } else {
                int u = task - 640;
                int hd = u & 7, cq = (u>>3)&3, t = u>>5;
                const int qrow = t*4 + cq;
                const float* qp = &qs[qrow*LDQ + 96 + hd*4];
                float q0 = qp[0], q1 = qp[1], q2 = qp[2], q3 = qp[3];
                float dots[4]; float mx = -1e30f;
#pragma unroll
                for (int ck = 0; ck < 4; ++ck) {
                    const float* kk = &qs[(t*4+ck)*LDQ + 128 + hd*4];
                    float dt = (q0*kk[0] + q1*kk[1] + q2*kk[2] + q3*kk[3]) * 0.5f;
                    dots[ck] = dt; mx = fmaxf(mx, dt);
                }
                float sum = 0.f;
#pragma unroll
                for (int ck = 0; ck < 4; ++ck) { float e = __expf(dots[ck]-mx); dots[ck] = e; sum += e; }
                const float inv = 1.f / sum;
                float o0=0.f,o1=0.f,o2=0.f,o3=0.f;
#pragma unroll
                for (int ck = 0; ck < 4; ++ck) {
                    const float* vv = &qs[(t*4+ck)*LDQ + 160 + hd*4];
                    float w = dots[ck];
                    o0 += w*vv[0]; o1 += w*vv[1]; o2 += w*vv[2]; o3 += w*vv[3];
                }
                float* op = &os[qrow*LDO + 32 + hd*4];
                op[0]=o0*inv; op[1]=o1*inv; op[2]=o2*inv; op[3]=o3*inv;
            }
        }
        __syncthreads();
        // ---- outproj (combined axes K=64) + biases + leaky -> hs ----
        for (int tile = wave; tile < 40; tile += 8) {
            int m = tile >> 3, n = tile & 7;
            f32x4 acc = (f32x4){0.f,0.f,0.f,0.f};
#pragma unroll
            for (int ks = 0; ks < 2; ++ks) {
                const float* ap = &os[(m*16 + l15)*LDO + ks*32 + quad*8];
                float4 x0 = *(const float4*)ap; float4 x1 = *(const float4*)(ap+4);
                bf16x8 af = pack8(x0.x,x0.y,x0.z,x0.w,x1.x,x1.y,x1.z,x1.w);
                bf16x8 bf = *(const bf16x8*)(wo + ((ks*8 + n)*64 + lane)*8);
                acc = __builtin_amdgcn_mfma_f32_16x16x32_bf16(af, bf, acc, 0, 0, 0);
            }
            int col = n*16 + l15;
            float bb = bout[(i*2+0)*128 + col] + bout[(i*2+1)*128 + col];
#pragma unroll
            for (int rg = 0; rg < 4; ++rg) {
                float v = acc[rg] + bb;
                v = v > 0.f ? v : 0.2f*v;
                hs[(m*16 + quad*4 + rg)*LDH + col] = v;
            }
        }
        __syncthreads();
    }

    // ---- decoder: dot(h_b, W_dec) + sigmoid ----
    float p = 0.f;
#pragma unroll
    for (int e = 0; e < 20; ++e) {
        int idx = tid + e*512;
        int r = idx >> 7, d = idx & 127;
        p += hs[r*LDH + d] * Wd[idx];
    }
#pragma unroll
    for (int off = 32; off > 0; off >>= 1) p += __shfl_down(p, off);
    if (lane == 0) red[wave] = p;
    __syncthreads();
    if (tid == 0) {
        float s = red[0]+red[1]+red[2]+red[3]+red[4]+red[5]+red[6]+red[7] + bd[0];
        out[b] = 1.f / (1.f + __expf(-s));
    }
}

extern "C" void kernel_launch(void* const* d_in, const int* in_sizes, int n_in,
                              void* d_out, int out_size, void* d_ws, size_t ws_size,
                              hipStream_t stream)
{
    (void)in_sizes; (void)n_in; (void)out_size; (void)ws_size;
    const float* x    = (const float*)d_in[0];
    const float* n1   = (const float*)d_in[1];
    const float* n2   = (const float*)d_in[2];
    const float* Wemb = (const float*)d_in[3];
    const float* bemb = (const float*)d_in[4];
    const float* Wq   = (const float*)d_in[5];
    const float* Wkv  = (const float*)d_in[6];
    const float* Wout = (const float*)d_in[7];
    const float* bout = (const float*)d_in[8];
    const float* Wd   = (const float*)d_in[9];
    const float* bd   = (const float*)d_in[10];
    float* out = (float*)d_out;

    char* ws = (char*)d_ws;
    unsigned short* frag = (unsigned short*)ws;            // 589,824 shorts = 1,179,648 B
    float* part = (float*)(ws + 1179648);                  // 2 x 10240 x 128 fp32 = 10,485,760 B

    prep_all<<<2304, 256, 0, stream>>>(Wemb, Wq, Wkv, Wout, frag);
    emb_kernel<<<1280, 256, 0, stream>>>(x, n1, n2, frag, part);
    mega_kernel<<<128, 512, 0, stream>>>(part, bemb, frag, bout, Wd, bd, out);
}